// Round 11
// baseline (147.360 us; speedup 1.0000x reference)
//
#include <hip/hip_runtime.h>

// Radon transform: data (1,1,512,512) f32, angles (256,) f32 -> out (1,1,256,512) f32.
// r11: r7 structure (f32 LDS tile gather, 35.8 KB single buffer, 4 blocks/CU,
// stride 95/97 by sign(c)) with staging REBUILT as coalesced reg-staged copy.
// Theory (fits r1-r10 + r3 + r8 quantitatively): global_load_lds issues PER-LANE
// 16B requests (no wave coalescing) -> 23 lanes x 92 rows x 8 chunks x 8 blocks
// = 135k L2 requests/CU ~= the entire 145-151k-cycle wall at ~1 req/cy TA rate.
// Every r1-r10 variant kept this staging -> identical ~60-66 us walls; r3 (+22%
// requests) -> +24% wall; r8 (scattered, ~650k lines) -> 205 us. Fix: all 512
// threads load the bbox FLAT via global_load_dwordx4 (consecutive lanes 16B
// apart -> wave coalesces to ~17 lines/instr, ~35k lines/CU total), then
// ds_write into the stride-95/97 tile. Prefetch regs (5 x f32x4 = 20 VGPR) are
// live ONLY inside the staging phase (r4's spill came from holding them across
// sampling). Sampling identical to r7 (fences + setprio + split acc).

#define HH 512
#define WW 512
#define NA 256
#define XC 64
#define YC 64
#define NXC (WW / XC)          // 8 x-chunks
#define NYC (HH / YC)          // 8 y-chunks
#define NW 8                   // waves per block
#define ROWS_MAX 92
#define SMAX 97
#define SEGW 23                // 16B segments per bbox row (23*16B = 92 dwords)
#define PAD 112                // >= 256*sqrt(2)-256+2
#define PW (WW + 2 * PAD)      // 736
#define PH (HH + 2 * PAD)      // 736

typedef float f32x2 __attribute__((ext_vector_type(2)));
typedef float f32x4 __attribute__((ext_vector_type(4)));

__global__ __launch_bounds__(256) void pad_kernel(
    const float* __restrict__ img, float* __restrict__ P)
{
    const int c = blockIdx.x * 256 + threadIdx.x;
    const int r = blockIdx.y;
    if (c >= PW) return;
    const int gr = r - PAD, gc = c - PAD;
    float v = 0.0f;
    if ((unsigned)gr < (unsigned)HH && (unsigned)gc < (unsigned)WW)
        v = img[gr * WW + gc];
    P[r * PW + c] = v;
}

__device__ __forceinline__ float fract_f(float x) {
#if __has_builtin(__builtin_amdgcn_fractf)
    return __builtin_amdgcn_fractf(x);
#else
    return x - floorf(x);
#endif
}

// 16B load with only 4B-known alignment; backend emits global_load_dwordx4
// (unaligned global access is legal). Consecutive lanes -> coalesced lines.
__device__ __forceinline__ f32x4 load4(const float* p) {
    f32x4 v;
    __builtin_memcpy(&v, p, 16);
    return v;
}

template <int STRIDE>
__device__ __forceinline__ void sample_chunk(
    const float* __restrict__ tb, const int c_lo, const int r_lo, const float v0,
    const float s, const float c, const float u, const int wid,
    f32x2& accA, f32x2& accB)
{
    const float bc = fmaf(c, u, 255.5f - (float)c_lo);
    const float br = fmaf(-s, u, 255.5f - (float)r_lo);
    const float vy0 = v0 + (float)(wid * 8);

    f32x2 base, stepv;
    base.x = fmaf(s, vy0, bc);     // local col coord, >= 0
    base.y = fmaf(c, vy0, br);     // local row coord, >= 0
    stepv.x = s;
    stepv.y = c;

    f32x2 k2, k3, k4;
    k2.x = 2.0f; k2.y = 2.0f;
    k3.x = 3.0f; k3.y = 3.0f;
    k4.x = 4.0f; k4.y = 4.0f;

#pragma unroll
    for (int g = 0; g < 2; ++g) {
        f32x2 crs[4];
        crs[0] = base;
        crs[1] = base + stepv;
        crs[2] = __builtin_elementwise_fma(stepv, k2, base);
        crs[3] = __builtin_elementwise_fma(stepv, k3, base);
        base = __builtin_elementwise_fma(stepv, k4, base);

        int ad[4];
        float wx[4], wy[4];
#pragma unroll
        for (int i = 0; i < 4; ++i) {
            const int ci = (int)crs[i].x;        // == floor for >= 0
            const int ri = (int)crs[i].y;
            wx[i] = fract_f(crs[i].x);
            wy[i] = fract_f(crs[i].y);
            __builtin_assume(ri >= 0 && ri < ROWS_MAX);
            __builtin_assume(ci >= 0 && ci < SMAX);
            ad[i] = ri * STRIDE + ci;
        }

        f32x2 top[4], bot[4];
#pragma unroll
        for (int i = 0; i < 4; ++i) {
            // ds_read2_b32 (0,1) and (STRIDE,STRIDE+1) -- immediates encodable
            top[i].x = tb[ad[i]];
            top[i].y = tb[ad[i] + 1];
            bot[i].x = tb[ad[i] + STRIDE];
            bot[i].y = tb[ad[i] + STRIDE + 1];
        }
        __builtin_amdgcn_sched_barrier(0);

        __builtin_amdgcn_s_setprio(1);
#pragma unroll
        for (int i = 0; i < 4; ++i) {
            f32x2 wyv;
            wyv.x = wy[i];
            wyv.y = wy[i];
            const f32x2 pv = __builtin_elementwise_fma(wyv, bot[i] - top[i], top[i]);
            f32x2 wxv;
            wxv.x = 1.0f - wx[i];
            wxv.y = wx[i];
            if (i & 1) accB = __builtin_elementwise_fma(wxv, pv, accB);
            else       accA = __builtin_elementwise_fma(wxv, pv, accA);
        }
        __builtin_amdgcn_s_setprio(0);
    }
}

template <bool PADDED, int STRIDE>
__device__ __forceinline__ void radon_body(
    const float* __restrict__ src, float* __restrict__ tile,
    const float s, const float c, const int lane, const int wid, const int x0,
    const int tid, f32x2& accA, f32x2& accB)
{
    constexpr bool CPOS = (STRIDE == 95);   // stride picked by sign(c)

    const float u  = (float)(x0 + lane) + (0.5f - 256.0f);
    const float u0 = (float)x0 + (0.5f - 256.0f);
    const float u1 = u0 + (float)(XC - 1);

    // origin-shifted padded base: valid for row/col indices in [-PAD, WW+PAD)
    const float* __restrict__ Porg = PADDED ? (src + PAD * PW + PAD) : src;

    for (int yc = 0; yc < NYC; ++yc) {
        const float v0 = (float)(yc * YC) + (0.5f - 256.0f);
        const float v1 = v0 + (float)(YC - 1);

        // sign(c) known at compile time (s >= 0 always): each bbox bound is
        // one affine expression -- no fmin/fmax trees (HW-verified r3/r4).
        float cx_min, cx_max, rx_min, rx_max;
        if (CPOS) {
            cx_min = fmaf(c, u0, fmaf(s, v0, 255.5f));
            cx_max = fmaf(c, u1, fmaf(s, v1, 255.5f));
            rx_min = fmaf(-s, u1, fmaf(c, v0, 255.5f));
            rx_max = fmaf(-s, u0, fmaf(c, v1, 255.5f));
        } else {
            cx_min = fmaf(c, u1, fmaf(s, v0, 255.5f));
            cx_max = fmaf(c, u0, fmaf(s, v1, 255.5f));
            rx_min = fmaf(-s, u1, fmaf(c, v1, 255.5f));
            rx_max = fmaf(-s, u0, fmaf(c, v0, 255.5f));
        }

        const int c_lo = (int)floorf(cx_min);
        const int c_hi = (int)floorf(cx_max) + 1;
        const int r_lo = (int)floorf(rx_min);
        const int r_hi = (int)floorf(rx_max) + 1;
        const int bh = min(r_hi - r_lo + 1, ROWS_MAX);

        // chunk entirely outside image -> contributes exactly 0 (zero padding)
        if (c_lo > WW - 1 || c_hi < 0 || r_lo > HH - 1 || r_hi < 0) continue;

        __syncthreads();   // previous chunk's sampling must finish before overwrite

        if (PADDED) {
            // COALESCED reg-staged copy: segment e in [0, bh*23) covers bbox
            // row r = e/23 (magic mul, valid e < 2116), 16B at col 4*(e-23r).
            // Global dword off = 4e + (PW-92)r (lanes 16B apart -> ~17 lines
            // per wave-load, vs 23 per-lane requests of global_load_lds).
            // LDS dword off = 4e + (STRIDE-92)r (max 8915 < 8924 alloc).
            // All staged addresses inside padded image ([-106,617] in [-112,624)).
            const int n = bh * SEGW;
            const float* gb = Porg + r_lo * PW + c_lo;
            f32x4 p0, p1, p2, p3, p4;
            const int e0 = tid, e1 = tid + 512, e2 = tid + 1024,
                      e3 = tid + 1536, e4 = tid + 2048;
            int r0 = 0, r1 = 0, r2 = 0, r3 = 0, r4 = 0;
            // issue all loads back-to-back (latency amortized once per chunk)
            if (e0 < n) { r0 = (int)(((unsigned)(e0 * 2850)) >> 16);
                          p0 = load4(gb + 4 * e0 + (PW - 4 * SEGW) * r0); }
            if (e1 < n) { r1 = (int)(((unsigned)(e1 * 2850)) >> 16);
                          p1 = load4(gb + 4 * e1 + (PW - 4 * SEGW) * r1); }
            if (e2 < n) { r2 = (int)(((unsigned)(e2 * 2850)) >> 16);
                          p2 = load4(gb + 4 * e2 + (PW - 4 * SEGW) * r2); }
            if (e3 < n) { r3 = (int)(((unsigned)(e3 * 2850)) >> 16);
                          p3 = load4(gb + 4 * e3 + (PW - 4 * SEGW) * r3); }
            if (e4 < n) { r4 = (int)(((unsigned)(e4 * 2850)) >> 16);
                          p4 = load4(gb + 4 * e4 + (PW - 4 * SEGW) * r4); }
            // write to tile (compiler inserts vmcnt waits; regs die here --
            // NOT held across sampling, so no r4-style spill)
#define STORE_SEG(E, R, P)                                                \
            if ((E) < n) {                                                \
                const int o = 4 * (E) + (STRIDE - 4 * SEGW) * (R);        \
                tile[o]     = (P).x;                                      \
                tile[o + 1] = (P).y;                                      \
                tile[o + 2] = (P).z;                                      \
                tile[o + 3] = (P).w;                                      \
            }
            STORE_SEG(e0, r0, p0)
            STORE_SEG(e1, r1, p1)
            STORE_SEG(e2, r2, p2)
            STORE_SEG(e3, r3, p3)
            STORE_SEG(e4, r4, p4)
#undef STORE_SEG
        } else {
            const int bw = min(c_hi - c_lo + 1, SMAX);
            for (int r = wid; r < bh; r += NW) {
                const int gr = r_lo + r;
                const bool row_ok = ((unsigned)gr < (unsigned)HH);
                const float* __restrict__ rowp = src + gr * WW;
                for (int cc = lane; cc < bw; cc += 64) {
                    const int gc = c_lo + cc;
                    float v = 0.0f;
                    if (row_ok) {
                        const int gcl = min(max(gc, 0), WW - 1);
                        const float t = rowp[gcl];
                        v = ((unsigned)gc < (unsigned)WW) ? t : 0.0f;
                    }
                    tile[r * STRIDE + cc] = v;
                }
            }
        }

        __syncthreads();

        sample_chunk<STRIDE>(tile, c_lo, r_lo, v0, s, c, u, wid, accA, accB);
    }
}

template <bool PADDED>
__global__ __launch_bounds__(512, 8) void radon_kernel(
    const float* __restrict__ src,   // PADDED ? padded image : raw image
    const float* __restrict__ angles, float* __restrict__ out)
{
    __shared__ float tile[ROWS_MAX * SMAX];   // 35.7 KB -> 4 blocks/CU (32 waves)

    const int tid  = threadIdx.x;
    const int lane = tid & 63;
    const int wid  = tid >> 6;     // 0..7

    const int a  = blockIdx.x >> 3;
    const int x0 = (blockIdx.x & 7) * XC;

    float s, c;
    sincosf(angles[a], &s, &c);

    // bank = (ri*stride + ci) % 32; stride 95 (== -1 mod 32) -> bank step c+s,
    // stride 97 (== +1) -> bank step c-s. s>=0: pick so |step| >= 1 always.
    // Block-uniform branch (same angle for whole block) -> __syncthreads safe.
    f32x2 accA, accB;
    accA.x = 0.0f; accA.y = 0.0f;
    accB.x = 0.0f; accB.y = 0.0f;
    if (c >= 0.0f)
        radon_body<PADDED, 95>(src, tile, s, c, lane, wid, x0, tid, accA, accB);
    else
        radon_body<PADDED, 97>(src, tile, s, c, lane, wid, x0, tid, accA, accB);

    // reduce the 8 y-groups per column and store (each block owns its outputs)
    __syncthreads();
    tile[tid] = (accA.x + accB.x) + (accA.y + accB.y);
    __syncthreads();
    if (tid < 64) {
        float r = tile[tid];
#pragma unroll
        for (int k = 1; k < NW; ++k) r += tile[k * 64 + tid];
        out[a * WW + x0 + tid] = r;
    }
}

extern "C" void kernel_launch(void* const* d_in, const int* in_sizes, int n_in,
                              void* d_out, int out_size, void* d_ws, size_t ws_size,
                              hipStream_t stream) {
    const float* img    = (const float*)d_in[0];
    const float* angles = (const float*)d_in[1];
    float* out = (float*)d_out;
    float* P   = (float*)d_ws;

    const bool padded = (ws_size >= (size_t)PW * PH * sizeof(float));

    if (padded) {
        pad_kernel<<<dim3((PW + 255) / 256, PH), 256, 0, stream>>>(img, P);
        radon_kernel<true><<<dim3(NA * NXC), 512, 0, stream>>>(P, angles, out);
    } else {
        radon_kernel<false><<<dim3(NA * NXC), 512, 0, stream>>>(img, angles, out);
    }
}

// Round 12
// 109.209 us; speedup vs baseline: 1.3493x; 1.3493x over previous
//
#include <hip/hip_runtime.h>

// Radon transform: data (1,1,512,512) f32, angles (256,) f32 -> out (1,1,256,512) f32.
// r12 = r7 (best measured: 60.6 us) + CONVOY-BREAKING BLOCK STAGGER.
// Evidence: across r0-r11 the wall is ~= max(VALU,LDS pipe) + ~45k cy/CU of sync
// overhead. The 4 co-resident blocks have consecutive blockIdx -> same angle,
// adjacent x0 -> IDENTICAL per-chunk timing -> lockstep: all stage (TA busy,
// LDS/VALU idle), all drain, all sample (LDS/VALU busy, TA idle). Fix: one-time
// s_sleep offset of (blockIdx&3) x 576 cycles (~quarter chunk period) desyncs
// the cohort; identical cadences preserve the offset, so at any instant ~1 block
// stages while 3 sample -> phases interleave across pipes. Worst-case cost if
// the convoy theory is wrong: ~2.9 us (8 sequential blocks x avg 864 cy).
// Everything else byte-identical to r7: 35.8 KB single LDS tile, 4 blocks/CU,
// stride 95/97 by sign(c) (bank step |c +- s| in [1,1.414]), global_load_lds
// width=16 staging, fenced 4-sample groups, split accumulators, setprio.

#define HH 512
#define WW 512
#define NA 256
#define XC 64
#define YC 64
#define NXC (WW / XC)          // 8 x-chunks
#define NYC (HH / YC)          // 8 y-chunks
#define NW 8                   // waves per block
#define ROWS_MAX 92
#define SMAX 97
#define PAD 112                // >= 256*sqrt(2)-256+2
#define PW (WW + 2 * PAD)      // 736
#define PH (HH + 2 * PAD)      // 736

typedef float f32x2 __attribute__((ext_vector_type(2)));

__global__ __launch_bounds__(256) void pad_kernel(
    const float* __restrict__ img, float* __restrict__ P)
{
    const int c = blockIdx.x * 256 + threadIdx.x;
    const int r = blockIdx.y;
    if (c >= PW) return;
    const int gr = r - PAD, gc = c - PAD;
    float v = 0.0f;
    if ((unsigned)gr < (unsigned)HH && (unsigned)gc < (unsigned)WW)
        v = img[gr * WW + gc];
    P[r * PW + c] = v;
}

__device__ __forceinline__ float fract_f(float x) {
#if __has_builtin(__builtin_amdgcn_fractf)
    return __builtin_amdgcn_fractf(x);
#else
    return x - floorf(x);
#endif
}

template <int STRIDE>
__device__ __forceinline__ void sample_chunk(
    const float* __restrict__ tb, const int c_lo, const int r_lo, const float v0,
    const float s, const float c, const float u, const int wid,
    f32x2& accA, f32x2& accB)
{
    const float bc = fmaf(c, u, 255.5f - (float)c_lo);
    const float br = fmaf(-s, u, 255.5f - (float)r_lo);
    const float vy0 = v0 + (float)(wid * 8);

    f32x2 base, stepv;
    base.x = fmaf(s, vy0, bc);     // local col coord, >= 0
    base.y = fmaf(c, vy0, br);     // local row coord, >= 0
    stepv.x = s;
    stepv.y = c;

    f32x2 k2, k3, k4;
    k2.x = 2.0f; k2.y = 2.0f;
    k3.x = 3.0f; k3.y = 3.0f;
    k4.x = 4.0f; k4.y = 4.0f;

#pragma unroll
    for (int g = 0; g < 2; ++g) {
        f32x2 crs[4];
        crs[0] = base;
        crs[1] = base + stepv;
        crs[2] = __builtin_elementwise_fma(stepv, k2, base);
        crs[3] = __builtin_elementwise_fma(stepv, k3, base);
        base = __builtin_elementwise_fma(stepv, k4, base);

        int ad[4];
        float wx[4], wy[4];
#pragma unroll
        for (int i = 0; i < 4; ++i) {
            const int ci = (int)crs[i].x;        // == floor for >= 0
            const int ri = (int)crs[i].y;
            wx[i] = fract_f(crs[i].x);
            wy[i] = fract_f(crs[i].y);
            __builtin_assume(ri >= 0 && ri < ROWS_MAX);
            __builtin_assume(ci >= 0 && ci < SMAX);
            ad[i] = ri * STRIDE + ci;
        }

        f32x2 top[4], bot[4];
#pragma unroll
        for (int i = 0; i < 4; ++i) {
            // ds_read2_b32 (0,1) and (STRIDE,STRIDE+1) -- immediates encodable
            top[i].x = tb[ad[i]];
            top[i].y = tb[ad[i] + 1];
            bot[i].x = tb[ad[i] + STRIDE];
            bot[i].y = tb[ad[i] + STRIDE + 1];
        }
        __builtin_amdgcn_sched_barrier(0);

        __builtin_amdgcn_s_setprio(1);
#pragma unroll
        for (int i = 0; i < 4; ++i) {
            f32x2 wyv;
            wyv.x = wy[i];
            wyv.y = wy[i];
            const f32x2 pv = __builtin_elementwise_fma(wyv, bot[i] - top[i], top[i]);
            f32x2 wxv;
            wxv.x = 1.0f - wx[i];
            wxv.y = wx[i];
            if (i & 1) accB = __builtin_elementwise_fma(wxv, pv, accB);
            else       accA = __builtin_elementwise_fma(wxv, pv, accA);
        }
        __builtin_amdgcn_s_setprio(0);
    }
}

template <bool PADDED, int STRIDE>
__device__ __forceinline__ void radon_body(
    const float* __restrict__ src, float* __restrict__ tile,
    const float s, const float c, const int lane, const int wid, const int x0,
    f32x2& accA, f32x2& accB)
{
    constexpr bool CPOS = (STRIDE == 95);   // stride picked by sign(c)

    const float u  = (float)(x0 + lane) + (0.5f - 256.0f);
    const float u0 = (float)x0 + (0.5f - 256.0f);
    const float u1 = u0 + (float)(XC - 1);

    // origin-shifted padded base: valid for row/col indices in [-PAD, WW+PAD)
    const float* __restrict__ Porg = PADDED ? (src + PAD * PW + PAD) : src;

    for (int yc = 0; yc < NYC; ++yc) {
        const float v0 = (float)(yc * YC) + (0.5f - 256.0f);
        const float v1 = v0 + (float)(YC - 1);

        // sign(c) known at compile time (s >= 0 always): each bbox bound is
        // one affine expression -- no fmin/fmax trees (HW-verified r3/r4).
        float cx_min, cx_max, rx_min, rx_max;
        if (CPOS) {
            cx_min = fmaf(c, u0, fmaf(s, v0, 255.5f));
            cx_max = fmaf(c, u1, fmaf(s, v1, 255.5f));
            rx_min = fmaf(-s, u1, fmaf(c, v0, 255.5f));
            rx_max = fmaf(-s, u0, fmaf(c, v1, 255.5f));
        } else {
            cx_min = fmaf(c, u1, fmaf(s, v0, 255.5f));
            cx_max = fmaf(c, u0, fmaf(s, v1, 255.5f));
            rx_min = fmaf(-s, u1, fmaf(c, v1, 255.5f));
            rx_max = fmaf(-s, u0, fmaf(c, v0, 255.5f));
        }

        const int c_lo = (int)floorf(cx_min);
        const int c_hi = (int)floorf(cx_max) + 1;
        const int r_lo = (int)floorf(rx_min);
        const int r_hi = (int)floorf(rx_max) + 1;
        const int bh = min(r_hi - r_lo + 1, ROWS_MAX);

        // chunk entirely outside image -> contributes exactly 0 (zero padding)
        if (c_lo > WW - 1 || c_hi < 0 || r_lo > HH - 1 || r_hi < 0) continue;

        __syncthreads();   // previous chunk's sampling must finish before overwrite

        if (PADDED) {
            // one global_load_lds_dwordx4 per bbox row: lanes 0..22 each move
            // 16 B -> LDS row base + lane*16 (368 B covers 92 dwords; <= STRIDE*4).
            // All staged addresses inside the padded image ([-106,617] in [-112,624)).
            if (lane < 23) {
                const float* g = Porg + (r_lo + wid) * PW + c_lo + lane * 4;
                float* l = &tile[wid * STRIDE];
                for (int r = wid; r < bh; r += NW) {
                    __builtin_amdgcn_global_load_lds(
                        (__attribute__((address_space(1))) const void*)g,
                        (__attribute__((address_space(3))) void*)l, 16, 0, 0);
                    g += NW * PW;
                    l += NW * STRIDE;
                }
            }
        } else {
            const int bw = min(c_hi - c_lo + 1, SMAX);
            for (int r = wid; r < bh; r += NW) {
                const int gr = r_lo + r;
                const bool row_ok = ((unsigned)gr < (unsigned)HH);
                const float* __restrict__ rowp = src + gr * WW;
                for (int cc = lane; cc < bw; cc += 64) {
                    const int gc = c_lo + cc;
                    float v = 0.0f;
                    if (row_ok) {
                        const int gcl = min(max(gc, 0), WW - 1);
                        const float t = rowp[gcl];
                        v = ((unsigned)gc < (unsigned)WW) ? t : 0.0f;
                    }
                    tile[r * STRIDE + cc] = v;
                }
            }
        }

        __syncthreads();

        sample_chunk<STRIDE>(tile, c_lo, r_lo, v0, s, c, u, wid, accA, accB);
    }
}

template <bool PADDED>
__global__ __launch_bounds__(512, 8) void radon_kernel(
    const float* __restrict__ src,   // PADDED ? padded image : raw image
    const float* __restrict__ angles, float* __restrict__ out)
{
    __shared__ float tile[ROWS_MAX * SMAX];   // 35.7 KB -> 4 blocks/CU (32 waves)

    const int tid  = threadIdx.x;
    const int lane = tid & 63;
    const int wid  = tid >> 6;     // 0..7

    const int a  = blockIdx.x >> 3;
    const int x0 = (blockIdx.x & 7) * XC;

    float s, c;
    sincosf(angles[a], &s, &c);

    // CONVOY BREAKER: one-time per-block phase offset of (bid&3) x 576 cycles
    // (~1/4 chunk period). Co-resident blocks are consecutive bids -> distinct
    // offsets; identical cadences afterwards preserve the stagger, so stage
    // (TA) and sample (LDS/VALU) phases interleave across the 4 blocks instead
    // of bursting in lockstep. s_sleep = pure stall, no sync semantics;
    // block-uniform -> barrier-safe.
    switch (blockIdx.x & 3) {
        case 1: asm volatile("s_sleep 9");  break;   // ~576 cy
        case 2: asm volatile("s_sleep 18"); break;   // ~1152 cy
        case 3: asm volatile("s_sleep 27"); break;   // ~1728 cy
        default: break;
    }

    // bank = (ri*stride + ci) % 32; stride 95 (== -1 mod 32) -> bank step c+s,
    // stride 97 (== +1) -> bank step c-s. s>=0: pick so |step| >= 1 always.
    // Block-uniform branch (same angle for whole block) -> __syncthreads safe.
    f32x2 accA, accB;
    accA.x = 0.0f; accA.y = 0.0f;
    accB.x = 0.0f; accB.y = 0.0f;
    if (c >= 0.0f)
        radon_body<PADDED, 95>(src, tile, s, c, lane, wid, x0, accA, accB);
    else
        radon_body<PADDED, 97>(src, tile, s, c, lane, wid, x0, accA, accB);

    // reduce the 8 y-groups per column and store (each block owns its outputs)
    __syncthreads();
    tile[tid] = (accA.x + accB.x) + (accA.y + accB.y);
    __syncthreads();
    if (tid < 64) {
        float r = tile[tid];
#pragma unroll
        for (int k = 1; k < NW; ++k) r += tile[k * 64 + tid];
        out[a * WW + x0 + tid] = r;
    }
}

extern "C" void kernel_launch(void* const* d_in, const int* in_sizes, int n_in,
                              void* d_out, int out_size, void* d_ws, size_t ws_size,
                              hipStream_t stream) {
    const float* img    = (const float*)d_in[0];
    const float* angles = (const float*)d_in[1];
    float* out = (float*)d_out;
    float* P   = (float*)d_ws;

    const bool padded = (ws_size >= (size_t)PW * PH * sizeof(float));

    if (padded) {
        pad_kernel<<<dim3((PW + 255) / 256, PH), 256, 0, stream>>>(img, P);
        radon_kernel<true><<<dim3(NA * NXC), 512, 0, stream>>>(P, angles, out);
    } else {
        radon_kernel<false><<<dim3(NA * NXC), 512, 0, stream>>>(img, angles, out);
    }
}

// Round 13
// 108.373 us; speedup vs baseline: 1.3597x; 1.0077x over previous
//
#include <hip/hip_runtime.h>

// Radon transform: data (1,1,512,512) f32, angles (256,) f32 -> out (1,1,256,512) f32.
// r13 = CONSOLIDATION: radon kernel is exact r7 (best measured 60.4-60.9 us over
// 13 rounds; r12's stagger rider removed -- proven null). Twelve rounds bracket
// a structural floor at ~60.5 us for this shape: VALU cut -20% -> -3% (r1); LDS
// reads/conflicts halved -> worse (r9); 8-deep asm-forced read pipeline -> null
// (r10); reg-staging -> spills at the 64-VGPR cap (r4/r11); occupancy trades
// -> -24% (r3); direct L2 gather -> TA-bound 3.4x worse (r8); block stagger ->
// null (r12). Remaining lever OUTSIDE radon: pad_kernel was scalar (Guideline
// 13 violation) -- now float4 vectorized: 1 dwordx4 load + 1 dwordx4 store per
// thread, 736 blocks x 192 thr (was 2208 x 256 scalar). Border quads (rare)
// take a scalar path; interior aligned (img rows 2KB-aligned, gc0 % 4 == 0).
// Radon structure: 35.8 KB single LDS tile, 4 blocks/CU = 32 waves (HW max),
// stride 95/97 by sign(c) -> per-lane bank step |c +- s| in [1,1.414],
// global_load_lds width=16 staging (1 instr/bbox row), fenced 4-sample groups,
// split accumulators, setprio around math.

#define HH 512
#define WW 512
#define NA 256
#define XC 64
#define YC 64
#define NXC (WW / XC)          // 8 x-chunks
#define NYC (HH / YC)          // 8 y-chunks
#define NW 8                   // waves per block
#define ROWS_MAX 92
#define SMAX 97
#define PAD 112                // >= 256*sqrt(2)-256+2
#define PW (WW + 2 * PAD)      // 736
#define PH (HH + 2 * PAD)      // 736

typedef float f32x2 __attribute__((ext_vector_type(2)));

// float4-vectorized zero-pad: thread q handles cols 4q..4q+3 of row r.
// Interior quads: one global_load_dwordx4 + one global_store_dwordx4
// (img row base 2KB-aligned and gc0 % 4 == 0 -> 16B-aligned; P likewise
// since PW % 4 == 0). Border quads take the scalar path (rare).
__global__ __launch_bounds__(192) void pad4_kernel(
    const float* __restrict__ img, float* __restrict__ P)
{
    const int r = blockIdx.x;          // 0..PH-1
    const int q = threadIdx.x;         // 0..191; PW/4 = 184 active
    if (q >= PW / 4) return;
    const int c0  = q * 4;
    const int gr  = r - PAD;
    const int gc0 = c0 - PAD;

    float4 v = make_float4(0.0f, 0.0f, 0.0f, 0.0f);
    if ((unsigned)gr < (unsigned)HH) {
        if (gc0 >= 0 && gc0 + 3 < WW) {
            v = *reinterpret_cast<const float4*>(&img[gr * WW + gc0]);
        } else {
            const float* rowp = img + gr * WW;
            float t[4];
#pragma unroll
            for (int i = 0; i < 4; ++i) {
                const int gc = gc0 + i;
                t[i] = ((unsigned)gc < (unsigned)WW) ? rowp[min(max(gc, 0), WW - 1)]
                                                     : 0.0f;
            }
            v = make_float4(t[0], t[1], t[2], t[3]);
        }
    }
    *reinterpret_cast<float4*>(&P[r * PW + c0]) = v;
}

__device__ __forceinline__ float fract_f(float x) {
#if __has_builtin(__builtin_amdgcn_fractf)
    return __builtin_amdgcn_fractf(x);
#else
    return x - floorf(x);
#endif
}

template <int STRIDE>
__device__ __forceinline__ void sample_chunk(
    const float* __restrict__ tb, const int c_lo, const int r_lo, const float v0,
    const float s, const float c, const float u, const int wid,
    f32x2& accA, f32x2& accB)
{
    const float bc = fmaf(c, u, 255.5f - (float)c_lo);
    const float br = fmaf(-s, u, 255.5f - (float)r_lo);
    const float vy0 = v0 + (float)(wid * 8);

    f32x2 base, stepv;
    base.x = fmaf(s, vy0, bc);     // local col coord, >= 0
    base.y = fmaf(c, vy0, br);     // local row coord, >= 0
    stepv.x = s;
    stepv.y = c;

    f32x2 k2, k3, k4;
    k2.x = 2.0f; k2.y = 2.0f;
    k3.x = 3.0f; k3.y = 3.0f;
    k4.x = 4.0f; k4.y = 4.0f;

#pragma unroll
    for (int g = 0; g < 2; ++g) {
        f32x2 crs[4];
        crs[0] = base;
        crs[1] = base + stepv;
        crs[2] = __builtin_elementwise_fma(stepv, k2, base);
        crs[3] = __builtin_elementwise_fma(stepv, k3, base);
        base = __builtin_elementwise_fma(stepv, k4, base);

        int ad[4];
        float wx[4], wy[4];
#pragma unroll
        for (int i = 0; i < 4; ++i) {
            const int ci = (int)crs[i].x;        // == floor for >= 0
            const int ri = (int)crs[i].y;
            wx[i] = fract_f(crs[i].x);
            wy[i] = fract_f(crs[i].y);
            __builtin_assume(ri >= 0 && ri < ROWS_MAX);
            __builtin_assume(ci >= 0 && ci < SMAX);
            ad[i] = ri * STRIDE + ci;
        }

        f32x2 top[4], bot[4];
#pragma unroll
        for (int i = 0; i < 4; ++i) {
            // ds_read2_b32 (0,1) and (STRIDE,STRIDE+1) -- immediates encodable
            top[i].x = tb[ad[i]];
            top[i].y = tb[ad[i] + 1];
            bot[i].x = tb[ad[i] + STRIDE];
            bot[i].y = tb[ad[i] + STRIDE + 1];
        }
        __builtin_amdgcn_sched_barrier(0);

        __builtin_amdgcn_s_setprio(1);
#pragma unroll
        for (int i = 0; i < 4; ++i) {
            f32x2 wyv;
            wyv.x = wy[i];
            wyv.y = wy[i];
            const f32x2 pv = __builtin_elementwise_fma(wyv, bot[i] - top[i], top[i]);
            f32x2 wxv;
            wxv.x = 1.0f - wx[i];
            wxv.y = wx[i];
            if (i & 1) accB = __builtin_elementwise_fma(wxv, pv, accB);
            else       accA = __builtin_elementwise_fma(wxv, pv, accA);
        }
        __builtin_amdgcn_s_setprio(0);
    }
}

template <bool PADDED, int STRIDE>
__device__ __forceinline__ void radon_body(
    const float* __restrict__ src, float* __restrict__ tile,
    const float s, const float c, const int lane, const int wid, const int x0,
    f32x2& accA, f32x2& accB)
{
    constexpr bool CPOS = (STRIDE == 95);   // stride picked by sign(c)

    const float u  = (float)(x0 + lane) + (0.5f - 256.0f);
    const float u0 = (float)x0 + (0.5f - 256.0f);
    const float u1 = u0 + (float)(XC - 1);

    // origin-shifted padded base: valid for row/col indices in [-PAD, WW+PAD)
    const float* __restrict__ Porg = PADDED ? (src + PAD * PW + PAD) : src;

    for (int yc = 0; yc < NYC; ++yc) {
        const float v0 = (float)(yc * YC) + (0.5f - 256.0f);
        const float v1 = v0 + (float)(YC - 1);

        // sign(c) known at compile time (s >= 0 always): each bbox bound is
        // one affine expression -- no fmin/fmax trees (HW-verified r3/r4).
        float cx_min, cx_max, rx_min, rx_max;
        if (CPOS) {
            cx_min = fmaf(c, u0, fmaf(s, v0, 255.5f));
            cx_max = fmaf(c, u1, fmaf(s, v1, 255.5f));
            rx_min = fmaf(-s, u1, fmaf(c, v0, 255.5f));
            rx_max = fmaf(-s, u0, fmaf(c, v1, 255.5f));
        } else {
            cx_min = fmaf(c, u1, fmaf(s, v0, 255.5f));
            cx_max = fmaf(c, u0, fmaf(s, v1, 255.5f));
            rx_min = fmaf(-s, u1, fmaf(c, v1, 255.5f));
            rx_max = fmaf(-s, u0, fmaf(c, v0, 255.5f));
        }

        const int c_lo = (int)floorf(cx_min);
        const int c_hi = (int)floorf(cx_max) + 1;
        const int r_lo = (int)floorf(rx_min);
        const int r_hi = (int)floorf(rx_max) + 1;
        const int bh = min(r_hi - r_lo + 1, ROWS_MAX);

        // chunk entirely outside image -> contributes exactly 0 (zero padding)
        if (c_lo > WW - 1 || c_hi < 0 || r_lo > HH - 1 || r_hi < 0) continue;

        __syncthreads();   // previous chunk's sampling must finish before overwrite

        if (PADDED) {
            // one global_load_lds_dwordx4 per bbox row: lanes 0..22 each move
            // 16 B -> LDS row base + lane*16 (368 B covers 92 dwords; <= STRIDE*4).
            // All staged addresses inside the padded image ([-106,617] in [-112,624)).
            if (lane < 23) {
                const float* g = Porg + (r_lo + wid) * PW + c_lo + lane * 4;
                float* l = &tile[wid * STRIDE];
                for (int r = wid; r < bh; r += NW) {
                    __builtin_amdgcn_global_load_lds(
                        (__attribute__((address_space(1))) const void*)g,
                        (__attribute__((address_space(3))) void*)l, 16, 0, 0);
                    g += NW * PW;
                    l += NW * STRIDE;
                }
            }
        } else {
            const int bw = min(c_hi - c_lo + 1, SMAX);
            for (int r = wid; r < bh; r += NW) {
                const int gr = r_lo + r;
                const bool row_ok = ((unsigned)gr < (unsigned)HH);
                const float* __restrict__ rowp = src + gr * WW;
                for (int cc = lane; cc < bw; cc += 64) {
                    const int gc = c_lo + cc;
                    float v = 0.0f;
                    if (row_ok) {
                        const int gcl = min(max(gc, 0), WW - 1);
                        const float t = rowp[gcl];
                        v = ((unsigned)gc < (unsigned)WW) ? t : 0.0f;
                    }
                    tile[r * STRIDE + cc] = v;
                }
            }
        }

        __syncthreads();

        sample_chunk<STRIDE>(tile, c_lo, r_lo, v0, s, c, u, wid, accA, accB);
    }
}

template <bool PADDED>
__global__ __launch_bounds__(512, 8) void radon_kernel(
    const float* __restrict__ src,   // PADDED ? padded image : raw image
    const float* __restrict__ angles, float* __restrict__ out)
{
    __shared__ float tile[ROWS_MAX * SMAX];   // 35.7 KB -> 4 blocks/CU (32 waves)

    const int tid  = threadIdx.x;
    const int lane = tid & 63;
    const int wid  = tid >> 6;     // 0..7

    const int a  = blockIdx.x >> 3;
    const int x0 = (blockIdx.x & 7) * XC;

    float s, c;
    sincosf(angles[a], &s, &c);

    // bank = (ri*stride + ci) % 32; stride 95 (== -1 mod 32) -> bank step c+s,
    // stride 97 (== +1) -> bank step c-s. s>=0: pick so |step| >= 1 always.
    // Block-uniform branch (same angle for whole block) -> __syncthreads safe.
    f32x2 accA, accB;
    accA.x = 0.0f; accA.y = 0.0f;
    accB.x = 0.0f; accB.y = 0.0f;
    if (c >= 0.0f)
        radon_body<PADDED, 95>(src, tile, s, c, lane, wid, x0, accA, accB);
    else
        radon_body<PADDED, 97>(src, tile, s, c, lane, wid, x0, accA, accB);

    // reduce the 8 y-groups per column and store (each block owns its outputs)
    __syncthreads();
    tile[tid] = (accA.x + accB.x) + (accA.y + accB.y);
    __syncthreads();
    if (tid < 64) {
        float r = tile[tid];
#pragma unroll
        for (int k = 1; k < NW; ++k) r += tile[k * 64 + tid];
        out[a * WW + x0 + tid] = r;
    }
}

extern "C" void kernel_launch(void* const* d_in, const int* in_sizes, int n_in,
                              void* d_out, int out_size, void* d_ws, size_t ws_size,
                              hipStream_t stream) {
    const float* img    = (const float*)d_in[0];
    const float* angles = (const float*)d_in[1];
    float* out = (float*)d_out;
    float* P   = (float*)d_ws;

    const bool padded = (ws_size >= (size_t)PW * PH * sizeof(float));

    if (padded) {
        pad4_kernel<<<dim3(PH), 192, 0, stream>>>(img, P);
        radon_kernel<true><<<dim3(NA * NXC), 512, 0, stream>>>(P, angles, out);
    } else {
        radon_kernel<false><<<dim3(NA * NXC), 512, 0, stream>>>(img, angles, out);
    }
}